// Round 6
// baseline (387.188 us; speedup 1.0000x reference)
//
#include <hip/hip_runtime.h>

#define BATCH 8
#define DIN   512
#define SEQ   8192
#define ECH   1024   // concatenated conv output channels (fore 512 | back 512)
#define HCH   256    // per-direction hidden channels
#define CL    32     // scan chunk length
#define NCHNK (SEQ / CL)   // 256 chunks per row
#define NSC   16           // superchunks (16 chunks each)

typedef __bf16 bf16;
typedef __bf16 bf16x8 __attribute__((ext_vector_type(8)));
typedef float  floatx4 __attribute__((ext_vector_type(4)));

__device__ __forceinline__ void async_ld16(void* lds, const void* g) {
  __builtin_amdgcn_global_load_lds(
      (const __attribute__((address_space(1))) unsigned int*)g,
      (__attribute__((address_space(3))) unsigned int*)lds, 16, 0, 0);
}

__device__ __forceinline__ float bits2f(unsigned u) {
  return __builtin_bit_cast(float, u);
}

// minGRU step: a = sigmoid(-g), bt = sigmoid(g) * (h>=0 ? 1+h : exp(h))
__device__ __forceinline__ void gru_ab(unsigned v, float& a, float& bt) {
  float hh = bits2f(v << 16);
  float g  = bits2f(v & 0xffff0000u);
  float eg = __expf(-g);
  float sg = 1.f / (1.f + eg);   // sigmoid(g)
  a = eg * sg;                    // sigmoid(-g)
  float gv = hh >= 0.f ? 1.f + hh : __expf(hh);
  bt = sg * gv;
}

// ---------------------------------------------------------------------------
// Kernel 1 (merged): blocks 0..2047 = weight convert/permute to
// MFMA-fragment-major bf16 (verified round 4/5); blocks 2048..10239 =
// tiled transpose/convert x[b,d,l] fp32 -> xT[b,l,d] bf16 (verified round 0).
// Merging saves one launch gap; wconv rides free next to the BW-bound xpose.
// Wf layout: element (n,d) at
//   Wf[ ((n>>4)*16 + (d>>5))*512 + (((d>>3)&3)*16 + (n&15))*8 + (d&7) ]
// ---------------------------------------------------------------------------
__global__ void k_prep(const float* __restrict__ x,
                       const float* __restrict__ wf, const float* __restrict__ bfo,
                       const float* __restrict__ wb, const float* __restrict__ bb,
                       bf16* __restrict__ xT, bf16* __restrict__ Wf,
                       float* __restrict__ bias) {
  __shared__ float T[64 * 65];
  int bid = blockIdx.x;
  int t = threadIdx.x;
  if (bid < 2048) {
    int idx = bid * 256 + t;
    if (idx < ECH * DIN) {
      int n = idx >> 9, d = idx & 511;
      int dir = n >> 9, r = n & 511, e = r >> 1, isg = r & 1;
      int s = e + (isg ? HCH : 0);
      const float* w = dir ? wb : wf;
      size_t o = ((size_t)((n >> 4) * 16 + (d >> 5)) << 9) +
                 ((((d >> 3) & 3) * 16 + (n & 15)) << 3) + (d & 7);
      Wf[o] = (bf16)w[s * DIN + d];
    }
    if (idx < ECH) {
      int dir = idx >> 9, r = idx & 511, e = r >> 1, isg = r & 1;
      int s = e + (isg ? HCH : 0);
      bias[idx] = (dir ? bb : bfo)[s];
    }
    return;
  }
  int id = bid - 2048;
  int l0 = (id & 127) * 64;
  int d0 = ((id >> 7) & 7) * 64;
  int b  = id >> 10;
  const float* xb = x + (size_t)b * DIN * SEQ;
#pragma unroll
  for (int p = 0; p < 4; ++p) {
    int dl = (t >> 4) + p * 16;
    int l4 = (t & 15) * 4;
    float4 v = *(const float4*)(xb + (size_t)(d0 + dl) * SEQ + l0 + l4);
    T[dl * 65 + l4 + 0] = v.x;
    T[dl * 65 + l4 + 1] = v.y;
    T[dl * 65 + l4 + 2] = v.z;
    T[dl * 65 + l4 + 3] = v.w;
  }
  __syncthreads();
  bf16* xTb = xT + (size_t)b * SEQ * DIN;
#pragma unroll
  for (int p = 0; p < 2; ++p) {
    int ll = (t >> 3) + p * 32;
    int d8 = (t & 7) * 8;
    bf16x8 h;
#pragma unroll
    for (int j = 0; j < 8; ++j) h[j] = (bf16)T[(d8 + j) * 65 + ll];
    *(bf16x8*)(xTb + (size_t)(l0 + ll) * DIN + d0 + d8) = h;
  }
}

// ---------------------------------------------------------------------------
// Kernel 2: bf16 MFMA GEMM  hg[b,l,n] = sum_d xT[b,l,d] * Wf[frag(n,d)] + bias[n]
// 128x128 tile, 4 waves (2x2), 16x16x32 frags. Round-5 verified skeleton
// (single A buffer, full __syncthreads drains, B from fragment-major global)
// with ONE change: BK=128 (4 K-tiles instead of 8) -> barrier count halves
// (8 vs 16) and the exposed A-staging latency hits the critical path 4x
// instead of 8x. LDS unchanged: As[128][128]=32KB, Cs[128][132] overlay.
// Swizzle generalized to 16 slots: LDS slot s of row r holds global col-slot
// s ^ (r&15); read slot = (k2*4+quad) ^ l15 (2 lanes/bank-quad = free).
// B-frags loaded in two k2-halves to cap bfr at 32 regs (no spill at (256,3)).
// Fused epilogue: bias+pack to Cs[128][132], hg store, per-chunk minGRU
// affine composition (A,B) straight from Cs.
// ---------------------------------------------------------------------------
#define BKK 128
#define NKT (DIN / BKK)     // 4 K-tiles

__launch_bounds__(256, 3)
__global__ void k_gemm(const bf16* __restrict__ xT, const bf16* __restrict__ Wf,
                       const float* __restrict__ bias, bf16* __restrict__ hg,
                       float* __restrict__ Asum, float* __restrict__ Bsum) {
  // staging: As[128][128] (16384 elems, 32KB); epilogue: Cs[128][132] overlay
  __shared__ __align__(16) bf16 lds[16896];
  bf16* As = lds;

  int t = threadIdx.x;
  int lane = t & 63, wave = t >> 6;
  int l15 = lane & 15, quad = lane >> 4;
  int wm = wave >> 1, wn = wave & 1;
  int mb = wm * 64, nb = wn * 64;

  // XCD-locality remap (round-0): all 8 n-tiles of one l-tile on one XCD.
  int lin = blockIdx.x + 8 * blockIdx.y;   // 0..511
  int xcd = lin & 7;
  int seq = lin >> 3;                      // 0..63
  int ltile = xcd + 8 * (seq >> 3);        // 0..63
  int ntile = seq & 7;
  int n0 = ntile * 128;
  int l0 = ltile * 128;
  int b  = blockIdx.z;

  const bf16* gA = xT + ((size_t)b * SEQ + l0) * DIN;
  int nb16 = (n0 >> 4) + wn * 4;           // this wave's base 16-row B block

  float bb4[4];
#pragma unroll
  for (int ni = 0; ni < 4; ++ni) bb4[ni] = bias[n0 + nb + ni * 16 + l15];

  floatx4 acc[4][4];
#pragma unroll
  for (int i = 0; i < 4; ++i)
#pragma unroll
    for (int j = 0; j < 4; ++j) acc[i][j] = (floatx4){0.f, 0.f, 0.f, 0.f};

#pragma unroll
  for (int kt = 0; kt < NKT; ++kt) {
    int k0 = kt * BKK;
    // stage A(kt): 8 global_load_lds per thread. Linear LDS dest
    // (wave-uniform base + lane*16B); source col-slot pre-swizzled so LDS
    // slot s of row r holds global slot s ^ (r&15).
#pragma unroll
    for (int j = 0; j < 8; ++j) {
      int i_ = t + j * 256;
      int row_ = i_ >> 4, slot_ = i_ & 15;
      async_ld16(As + (size_t)i_ * 8,
                 gA + (size_t)row_ * DIN + k0 + ((slot_ ^ (row_ & 15)) * 8));
    }

    // B fragments, first k2-half (k2=0,1): 8 coalesced 1KB wave-loads,
    // issued before the drain so latency overlaps it.
    bf16x8 bfr[4][2];
#pragma unroll
    for (int i = 0; i < 4; ++i)
#pragma unroll
      for (int k2 = 0; k2 < 2; ++k2)
        bfr[i][k2] = *(const bf16x8*)(Wf +
            (((size_t)(nb16 + i) * 16 + kt * 4 + k2) << 9) + lane * 8);

    __syncthreads();   // full drain: all waves' A(kt) visible in LDS

#pragma unroll
    for (int k2 = 0; k2 < 2; ++k2) {
      bf16x8 af[4];
#pragma unroll
      for (int i = 0; i < 4; ++i)
        af[i] = *(const bf16x8*)(As + (size_t)(mb + i * 16 + l15) * 128 +
                                 (((k2 * 4 + quad) ^ l15) * 8));
#pragma unroll
      for (int mi = 0; mi < 4; ++mi)
#pragma unroll
        for (int ni = 0; ni < 4; ++ni)
          acc[mi][ni] = __builtin_amdgcn_mfma_f32_16x16x32_bf16(
              af[mi], bfr[ni][k2], acc[mi][ni], 0, 0, 0);
    }

    // second k2-half (k2=2,3)
#pragma unroll
    for (int i = 0; i < 4; ++i)
#pragma unroll
      for (int k2 = 0; k2 < 2; ++k2)
        bfr[i][k2] = *(const bf16x8*)(Wf +
            (((size_t)(nb16 + i) * 16 + kt * 4 + 2 + k2) << 9) + lane * 8);
#pragma unroll
    for (int k2 = 0; k2 < 2; ++k2) {
      bf16x8 af[4];
#pragma unroll
      for (int i = 0; i < 4; ++i)
        af[i] = *(const bf16x8*)(As + (size_t)(mb + i * 16 + l15) * 128 +
                                 ((((k2 + 2) * 4 + quad) ^ l15) * 8));
#pragma unroll
      for (int mi = 0; mi < 4; ++mi)
#pragma unroll
        for (int ni = 0; ni < 4; ++ni)
          acc[mi][ni] = __builtin_amdgcn_mfma_f32_16x16x32_bf16(
              af[mi], bfr[ni][k2], acc[mi][ni], 0, 0, 0);
    }
    __syncthreads();   // all reads done before next tile's overwrite
  }

  // epilogue: bias add, pack to bf16 in LDS (stride 132 breaks conflicts), store
  bf16* Cs = lds;  // [128][132]
#pragma unroll
  for (int mi = 0; mi < 4; ++mi)
#pragma unroll
    for (int ni = 0; ni < 4; ++ni)
#pragma unroll
      for (int r = 0; r < 4; ++r) {
        int row = mb + mi * 16 + quad * 4 + r;
        int col = nb + ni * 16 + l15;
        Cs[row * 132 + col] = (bf16)(acc[mi][ni][r] + bb4[ni]);
      }
  __syncthreads();
  bf16* hgb = hg + ((size_t)b * SEQ + l0) * ECH + n0;
#pragma unroll
  for (int p = 0; p < 8; ++p) {
    int row = p * 16 + (t >> 4);
    int seg = t & 15;
    *(bf16x8*)(hgb + (size_t)row * ECH + seg * 8) =
        *(const bf16x8*)(Cs + row * 132 + seg * 8);
  }

  // fused per-chunk minGRU composition
  // wave = chunk within tile (4 chunks of 32), lane = e-pair within tile (64)
  {
    int dirn = ntile >> 2;               // n0 >> 9
    int c = wave, el = lane;
    float A = 1.f, Bc = 0.f;
#pragma unroll 8
    for (int i = 0; i < CL; ++i) {
      int row = c * CL + (dirn ? (CL - 1 - i) : i);
      unsigned v = *(const unsigned*)(Cs + row * 132 + 2 * el);
      float a, bt;
      gru_ab(v, a, bt);
      A *= a;
      Bc = a * Bc + bt;
    }
    int chunkg = ltile * 4 + c;
    int eg = ((n0 & 511) >> 1) + el;
    size_t o = ((size_t)(b * 2 + dirn) * NCHNK + chunkg) * 256 + eg;
    Asum[o] = A;
    Bsum[o] = Bc;
  }
}

// ---------------------------------------------------------------------------
// Kernel 3a: per-superchunk (16 chunks) composition. 256 blocks x 256 thr.
// (round-0 proven; the 16-block merged variant measured +16.5 us slower)
// ---------------------------------------------------------------------------
__global__ void k_scan2a(const float* __restrict__ Asum, const float* __restrict__ Bsum,
                         float* __restrict__ SA, float* __restrict__ SB) {
  int e = threadIdx.x, sc = blockIdx.x, row2 = blockIdx.y, dir = row2 & 1;
  size_t base = (size_t)row2 * NCHNK;
  float Acc = 1.f, Bcc = 0.f;
#pragma unroll
  for (int i = 0; i < 16; ++i) {
    int c = sc * 16 + (dir ? 15 - i : i);
    size_t o = (base + c) * 256 + e;
    float a = Asum[o], bv = Bsum[o];
    Acc = a * Acc;
    Bcc = a * Bcc + bv;
  }
  size_t so = ((size_t)row2 * NSC + sc) * 256 + e;
  SA[so] = Acc;
  SB[so] = Bcc;
}

// ---------------------------------------------------------------------------
// Kernel 3b: scan the 16 superchunks per row. 16 blocks x 256 thr.
// ---------------------------------------------------------------------------
__global__ void k_scan2b(const float* __restrict__ SA, const float* __restrict__ SB,
                         float* __restrict__ hsc) {
  int e = threadIdx.x, row2 = blockIdx.x, dir = row2 & 1;
  float h = 0.f;
  for (int i = 0; i < NSC; ++i) {
    int sc = dir ? NSC - 1 - i : i;
    size_t o = ((size_t)row2 * NSC + sc) * 256 + e;
    hsc[o] = h;
    h = SA[o] * h + SB[o];
  }
}

// ---------------------------------------------------------------------------
// Kernel 3c: distribute carries to every chunk. 256 blocks x 256 thr.
// ---------------------------------------------------------------------------
__global__ void k_scan2c(const float* __restrict__ Asum, const float* __restrict__ Bsum,
                         const float* __restrict__ hsc, float* __restrict__ hin) {
  int e = threadIdx.x, sc = blockIdx.x, row2 = blockIdx.y, dir = row2 & 1;
  float h = hsc[((size_t)row2 * NSC + sc) * 256 + e];
#pragma unroll
  for (int i = 0; i < 16; ++i) {
    int c = sc * 16 + (dir ? 15 - i : i);
    size_t o = ((size_t)row2 * NCHNK + c) * 256 + e;
    hin[o] = h;
    h = Asum[o] * h + Bsum[o];
  }
}

// ---------------------------------------------------------------------------
// Kernel 4: recompute local scan with carry-in, transpose via LDS (stride 33),
// write out[b, dir*256+e, l] as coalesced float4.
// ---------------------------------------------------------------------------
__global__ void k_scan3(const bf16* __restrict__ hg, const float* __restrict__ hin,
                        float* __restrict__ out) {
  __shared__ float T[256 * 33];
  int t = threadIdx.x;
  int chunk = blockIdx.x, dir = blockIdx.y, b = blockIdx.z;
  const bf16* hb = hg + (size_t)b * SEQ * ECH + dir * 512 + 2 * t;
  float h = hin[((size_t)(b * 2 + dir) * NCHNK + chunk) * 256 + t];
  int lbase = chunk * CL;
#pragma unroll 8
  for (int i = 0; i < CL; ++i) {
    int ll = dir ? (CL - 1 - i) : i;
    unsigned v = *(const unsigned*)(hb + (size_t)(lbase + ll) * ECH);
    float a, bt;
    gru_ab(v, a, bt);
    h = a * h + bt;
    T[t * 33 + ll] = h;
  }
  __syncthreads();
  float* ob = out + ((size_t)b * 512 + dir * 256) * SEQ + lbase;
#pragma unroll
  for (int p = 0; p < 8; ++p) {
    int row = p * 32 + (t >> 3);   // e channel
    int c4 = (t & 7) * 4;          // l within chunk
    float4 v4;
    v4.x = T[row * 33 + c4 + 0];
    v4.y = T[row * 33 + c4 + 1];
    v4.z = T[row * 33 + c4 + 2];
    v4.w = T[row * 33 + c4 + 3];
    *(float4*)(ob + (size_t)row * SEQ + c4) = v4;
  }
}

// ---------------------------------------------------------------------------
extern "C" void kernel_launch(void* const* d_in, const int* in_sizes, int n_in,
                              void* d_out, int out_size, void* d_ws, size_t ws_size,
                              hipStream_t stream) {
  const float* x   = (const float*)d_in[0];
  const float* wf  = (const float*)d_in[1];
  const float* bfo = (const float*)d_in[2];
  const float* wb  = (const float*)d_in[3];
  const float* bb  = (const float*)d_in[4];
  float* out = (float*)d_out;
  char* ws = (char*)d_ws;

  // workspace layout (bytes):
  bf16*  xT   = (bf16*)(ws);                       // 67,108,864
  bf16*  hg   = (bf16*)(ws + 67108864);            // 134,217,728
  bf16*  Wfm  = (bf16*)(ws + 201326592);           // 1,048,576
  float* bias = (float*)(ws + 202375168);          // 4,096
  float* Asum = (float*)(ws + 202379264);          // 4,194,304
  float* Bsum = (float*)(ws + 206573568);          // 4,194,304
  float* hin  = (float*)(ws + 210767872);          // 4,194,304
  float* SA   = (float*)(ws + 214962176);          // 262,144
  float* SB   = (float*)(ws + 215224320);          // 262,144
  float* hsc  = (float*)(ws + 215486464);          // 262,144  (total ~215.7 MB)

  k_prep<<<10240, 256, 0, stream>>>(x, wf, bfo, wb, bb, xT, Wfm, bias);
  k_gemm<<<dim3(ECH / 128, SEQ / 128, BATCH), 256, 0, stream>>>(xT, Wfm, bias, hg,
                                                                Asum, Bsum);
  k_scan2a<<<dim3(NSC, 16), 256, 0, stream>>>(Asum, Bsum, SA, SB);
  k_scan2b<<<16, 256, 0, stream>>>(SA, SB, hsc);
  k_scan2c<<<dim3(NSC, 16), 256, 0, stream>>>(Asum, Bsum, hsc, hin);
  k_scan3<<<dim3(NCHNK, 2, BATCH), 256, 0, stream>>>(hg, hin, out);
}

// Round 7
// 382.178 us; speedup vs baseline: 1.0131x; 1.0131x over previous
//
#include <hip/hip_runtime.h>

#define BATCH 8
#define DIN   512
#define SEQ   8192
#define ECH   1024   // concatenated conv output channels (fore 512 | back 512)
#define HCH   256    // per-direction hidden channels
#define CL    32     // scan chunk length
#define NCHNK (SEQ / CL)   // 256 chunks per row
#define NSC   16           // superchunks (16 chunks each)

typedef __bf16 bf16;
typedef __bf16 bf16x8 __attribute__((ext_vector_type(8)));
typedef float  floatx4 __attribute__((ext_vector_type(4)));

__device__ __forceinline__ void async_ld16(void* lds, const void* g) {
  __builtin_amdgcn_global_load_lds(
      (const __attribute__((address_space(1))) unsigned int*)g,
      (__attribute__((address_space(3))) unsigned int*)lds, 16, 0, 0);
}

__device__ __forceinline__ float bits2f(unsigned u) {
  return __builtin_bit_cast(float, u);
}

// minGRU step: a = sigmoid(-g), bt = sigmoid(g) * (h>=0 ? 1+h : exp(h))
__device__ __forceinline__ void gru_ab(unsigned v, float& a, float& bt) {
  float hh = bits2f(v << 16);
  float g  = bits2f(v & 0xffff0000u);
  float eg = __expf(-g);
  float sg = 1.f / (1.f + eg);   // sigmoid(g)
  a = eg * sg;                    // sigmoid(-g)
  float gv = hh >= 0.f ? 1.f + hh : __expf(hh);
  bt = sg * gv;
}

// ---------------------------------------------------------------------------
// Kernel 1: convert/permute weights to bf16 in MFMA-FRAGMENT-MAJOR order:
// element (n,d) at
//   Wf[ ((n>>4)*16 + (d>>5))*512 + (((d>>3)&3)*16 + (n&15))*8 + (d&7) ]
// so one wave's fragment load is a single contiguous 1 KB global_load_dwordx4
// -> B never needs LDS staging. (Verified rounds 4/5.)
// ---------------------------------------------------------------------------
__global__ void k_wconv(const float* __restrict__ wf, const float* __restrict__ bfo,
                        const float* __restrict__ wb, const float* __restrict__ bb,
                        bf16* __restrict__ Wf, float* __restrict__ bias) {
  int idx = blockIdx.x * 256 + threadIdx.x;
  if (idx < ECH * DIN) {
    int n = idx >> 9, d = idx & 511;
    int dir = n >> 9, r = n & 511, e = r >> 1, isg = r & 1;
    int s = e + (isg ? HCH : 0);
    const float* w = dir ? wb : wf;
    size_t o = ((size_t)((n >> 4) * 16 + (d >> 5)) << 9) +
               ((((d >> 3) & 3) * 16 + (n & 15)) << 3) + (d & 7);
    Wf[o] = (bf16)w[s * DIN + d];
  }
  if (idx < ECH) {
    int dir = idx >> 9, r = idx & 511, e = r >> 1, isg = r & 1;
    int s = e + (isg ? HCH : 0);
    bias[idx] = (dir ? bb : bfo)[s];
  }
}

// ---------------------------------------------------------------------------
// Kernel 2: tiled transpose + convert  x[b,d,l] fp32 -> xT[b,l,d] bf16
// (round-0 verbatim; the merged-prep variant measured +6 us slower)
// ---------------------------------------------------------------------------
__global__ void k_xpose(const float* __restrict__ x, bf16* __restrict__ xT) {
  __shared__ float T[64 * 65];
  int t = threadIdx.x;
  int l0 = blockIdx.x * 64;
  int d0 = blockIdx.y * 64;
  int b  = blockIdx.z;
  const float* xb = x + (size_t)b * DIN * SEQ;
#pragma unroll
  for (int p = 0; p < 4; ++p) {
    int dl = (t >> 4) + p * 16;
    int l4 = (t & 15) * 4;
    float4 v = *(const float4*)(xb + (size_t)(d0 + dl) * SEQ + l0 + l4);
    T[dl * 65 + l4 + 0] = v.x;
    T[dl * 65 + l4 + 1] = v.y;
    T[dl * 65 + l4 + 2] = v.z;
    T[dl * 65 + l4 + 3] = v.w;
  }
  __syncthreads();
  bf16* xTb = xT + (size_t)b * SEQ * DIN;
#pragma unroll
  for (int p = 0; p < 2; ++p) {
    int ll = (t >> 3) + p * 32;
    int d8 = (t & 7) * 8;
    bf16x8 h;
#pragma unroll
    for (int j = 0; j < 8; ++j) h[j] = (bf16)T[(d8 + j) * 65 + ll];
    *(bf16x8*)(xTb + (size_t)(l0 + ll) * DIN + d0 + d8) = h;
  }
}

// ---------------------------------------------------------------------------
// Kernel 3: bf16 MFMA GEMM + fused minGRU prefix epilogue.
// 128x128 tile, 4 waves (2x2), BK=64, 16x16x32 frags. ROUND-5 VERIFIED
// skeleton (single A buffer, full __syncthreads drains, B from fragment-major
// global, (256,3) no-spill). ONE epilogue change: instead of storing hg and
// recomputing a,bt in scan3, the composition loop stores the RUNNING PREFIX
// (A_pfx, B_pfx) per element as packed bf16x2 in P[row2][l][e] (same bytes
// as hg). scan3 then needs zero transcendentals: h = A_pfx*h0 + B_pfx.
// Long-range chain (Asum/Bsum) stays fp32 -> only local combine sees bf16
// rounding. Per-iter P write: 64 lanes x 4B consecutive = 256B coalesced.
// ---------------------------------------------------------------------------
#define BKK 64
#define NKT (DIN / BKK)     // 8 K-tiles

__launch_bounds__(256, 3)
__global__ void k_gemm(const bf16* __restrict__ xT, const bf16* __restrict__ Wf,
                       const float* __restrict__ bias, unsigned* __restrict__ P,
                       float* __restrict__ Asum, float* __restrict__ Bsum) {
  // staging: As[128][64] (8192 elems); epilogue: Cs[128][132] overlay
  __shared__ __align__(16) bf16 lds[16896];
  bf16* As = lds;

  int t = threadIdx.x;
  int lane = t & 63, wave = t >> 6;
  int l15 = lane & 15, quad = lane >> 4, rsw = l15 & 7;
  int wm = wave >> 1, wn = wave & 1;
  int mb = wm * 64, nb = wn * 64;

  // XCD-locality remap (round-0): all 8 n-tiles of one l-tile on one XCD.
  int lin = blockIdx.x + 8 * blockIdx.y;   // 0..511
  int xcd = lin & 7;
  int seq = lin >> 3;                      // 0..63
  int ltile = xcd + 8 * (seq >> 3);        // 0..63
  int ntile = seq & 7;
  int n0 = ntile * 128;
  int l0 = ltile * 128;
  int b  = blockIdx.z;

  const bf16* gA = xT + ((size_t)b * SEQ + l0) * DIN;
  int nb16 = (n0 >> 4) + wn * 4;           // this wave's base 16-row B block

  float bb4[4];
#pragma unroll
  for (int ni = 0; ni < 4; ++ni) bb4[ni] = bias[n0 + nb + ni * 16 + l15];

  int srow = wave * 32 + (lane >> 3);
  int scol = ((lane & 7) ^ ((lane >> 3) & 7)) * 8;   // XOR-preswizzled src col

  floatx4 acc[4][4];
#pragma unroll
  for (int i = 0; i < 4; ++i)
#pragma unroll
    for (int j = 0; j < 4; ++j) acc[i][j] = (floatx4){0.f, 0.f, 0.f, 0.f};

#pragma unroll
  for (int kt = 0; kt < NKT; ++kt) {
    int k0 = kt * BKK;
    // stage A(kt): 4 global_load_lds per thread, linear LDS dest
    // (wave-uniform base + lane*16B), XOR-preswizzled global source col.
#pragma unroll
    for (int q = 0; q < 4; ++q)
      async_ld16(As + (wave * 32 + q * 8) * 64,
                 gA + (size_t)(srow + q * 8) * DIN + k0 + scol);

    // B fragments for this K-tile: 8 coalesced 1KB wave-loads from L2.
    // Issued before the drain so their latency overlaps it.
    bf16x8 bfr[4][2];
#pragma unroll
    for (int i = 0; i < 4; ++i)
#pragma unroll
      for (int k2 = 0; k2 < 2; ++k2)
        bfr[i][k2] = *(const bf16x8*)(Wf +
            (((size_t)(nb16 + i) * 16 + kt * 2 + k2) << 9) + lane * 8);

    __syncthreads();   // full drain: all waves' A(kt) visible in LDS

#pragma unroll
    for (int k2 = 0; k2 < 2; ++k2) {
      bf16x8 af[4];
#pragma unroll
      for (int i = 0; i < 4; ++i)
        af[i] = *(const bf16x8*)(As + (mb + i * 16 + l15) * 64 +
                                 (((k2 * 4 + quad) ^ rsw) * 8));
#pragma unroll
      for (int mi = 0; mi < 4; ++mi)
#pragma unroll
        for (int ni = 0; ni < 4; ++ni)
          acc[mi][ni] = __builtin_amdgcn_mfma_f32_16x16x32_bf16(
              af[mi], bfr[ni][k2], acc[mi][ni], 0, 0, 0);
    }
    __syncthreads();   // all reads done before next tile's overwrite
  }

  // epilogue: bias add, pack to bf16 in LDS (stride 132 breaks conflicts)
  bf16* Cs = lds;  // [128][132]
#pragma unroll
  for (int mi = 0; mi < 4; ++mi)
#pragma unroll
    for (int ni = 0; ni < 4; ++ni)
#pragma unroll
      for (int r = 0; r < 4; ++r) {
        int row = mb + mi * 16 + quad * 4 + r;
        int col = nb + ni * 16 + l15;
        Cs[row * 132 + col] = (bf16)(acc[mi][ni][r] + bb4[ni]);
      }
  __syncthreads();

  // fused per-chunk minGRU composition + per-element prefix store.
  // wave = chunk within tile (4 chunks of 32), lane = e-pair within tile (64)
  {
    int dirn = ntile >> 2;               // n0 >> 9
    int c = wave, el = lane;
    int chunkg = ltile * 4 + c;
    int eg = ((n0 & 511) >> 1) + el;
    int row2 = b * 2 + dirn;
    unsigned* Pr = P + ((size_t)row2 * SEQ + (size_t)chunkg * CL) * 256 + eg;
    float A = 1.f, Bc = 0.f;
#pragma unroll 8
    for (int i = 0; i < CL; ++i) {
      int ll = dirn ? (CL - 1 - i) : i;
      unsigned v = *(const unsigned*)(Cs + (c * CL + ll) * 132 + 2 * el);
      float a, bt;
      gru_ab(v, a, bt);
      A *= a;
      Bc = a * Bc + bt;
      unsigned lo = (unsigned)__builtin_bit_cast(unsigned short, (bf16)A);
      unsigned hi = (unsigned)__builtin_bit_cast(unsigned short, (bf16)Bc);
      Pr[(size_t)ll * 256] = (hi << 16) | lo;   // 64 lanes -> 256B coalesced
    }
    size_t o = ((size_t)row2 * NCHNK + chunkg) * 256 + eg;
    Asum[o] = A;
    Bsum[o] = Bc;
  }
}

// ---------------------------------------------------------------------------
// Kernel 4a: per-superchunk (16 chunks) composition. 256 blocks x 256 thr.
// ---------------------------------------------------------------------------
__global__ void k_scan2a(const float* __restrict__ Asum, const float* __restrict__ Bsum,
                         float* __restrict__ SA, float* __restrict__ SB) {
  int e = threadIdx.x, sc = blockIdx.x, row2 = blockIdx.y, dir = row2 & 1;
  size_t base = (size_t)row2 * NCHNK;
  float Acc = 1.f, Bcc = 0.f;
#pragma unroll
  for (int i = 0; i < 16; ++i) {
    int c = sc * 16 + (dir ? 15 - i : i);
    size_t o = (base + c) * 256 + e;
    float a = Asum[o], bv = Bsum[o];
    Acc = a * Acc;
    Bcc = a * Bcc + bv;
  }
  size_t so = ((size_t)row2 * NSC + sc) * 256 + e;
  SA[so] = Acc;
  SB[so] = Bcc;
}

// ---------------------------------------------------------------------------
// Kernel 4b: scan the 16 superchunks per row. 16 blocks x 256 thr.
// ---------------------------------------------------------------------------
__global__ void k_scan2b(const float* __restrict__ SA, const float* __restrict__ SB,
                         float* __restrict__ hsc) {
  int e = threadIdx.x, row2 = blockIdx.x, dir = row2 & 1;
  float h = 0.f;
  for (int i = 0; i < NSC; ++i) {
    int sc = dir ? NSC - 1 - i : i;
    size_t o = ((size_t)row2 * NSC + sc) * 256 + e;
    hsc[o] = h;
    h = SA[o] * h + SB[o];
  }
}

// ---------------------------------------------------------------------------
// Kernel 4c: distribute carries to every chunk. 256 blocks x 256 thr.
// ---------------------------------------------------------------------------
__global__ void k_scan2c(const float* __restrict__ Asum, const float* __restrict__ Bsum,
                         const float* __restrict__ hsc, float* __restrict__ hin) {
  int e = threadIdx.x, sc = blockIdx.x, row2 = blockIdx.y, dir = row2 & 1;
  float h = hsc[((size_t)row2 * NSC + sc) * 256 + e];
#pragma unroll
  for (int i = 0; i < 16; ++i) {
    int c = sc * 16 + (dir ? 15 - i : i);
    size_t o = ((size_t)row2 * NCHNK + c) * 256 + e;
    hin[o] = h;
    h = Asum[o] * h + Bsum[o];
  }
}

// ---------------------------------------------------------------------------
// Kernel 5: ELEMENTWISE carry combine: h[l] = A_pfx[l]*h0 + B_pfx[l] from the
// packed prefix buffer P (no transcendentals, no serial chain). Transpose via
// LDS (stride 33), write out[b, dir*256+e, l] as coalesced float4.
// ---------------------------------------------------------------------------
__global__ void k_scan3(const unsigned* __restrict__ P, const float* __restrict__ hin,
                        float* __restrict__ out) {
  __shared__ float T[256 * 33];
  int t = threadIdx.x;
  int chunk = blockIdx.x, dir = blockIdx.y, b = blockIdx.z;
  int row2 = b * 2 + dir;
  const unsigned* Pb = P + ((size_t)row2 * SEQ + (size_t)chunk * CL) * 256 + t;
  float h0 = hin[((size_t)row2 * NCHNK + chunk) * 256 + t];
  int lbase = chunk * CL;
#pragma unroll
  for (int ll = 0; ll < CL; ++ll) {
    unsigned v = Pb[(size_t)ll * 256];          // 64 lanes -> 256B coalesced
    float a  = bits2f(v << 16);                 // A_pfx (low bf16)
    float bt = bits2f(v & 0xffff0000u);         // B_pfx (high bf16)
    T[t * 33 + ll] = a * h0 + bt;
  }
  __syncthreads();
  float* ob = out + ((size_t)b * 512 + dir * 256) * SEQ + lbase;
#pragma unroll
  for (int p = 0; p < 8; ++p) {
    int row = p * 32 + (t >> 3);   // e channel
    int c4 = (t & 7) * 4;          // l within chunk
    float4 v4;
    v4.x = T[row * 33 + c4 + 0];
    v4.y = T[row * 33 + c4 + 1];
    v4.z = T[row * 33 + c4 + 2];
    v4.w = T[row * 33 + c4 + 3];
    *(float4*)(ob + (size_t)row * SEQ + c4) = v4;
  }
}

// ---------------------------------------------------------------------------
extern "C" void kernel_launch(void* const* d_in, const int* in_sizes, int n_in,
                              void* d_out, int out_size, void* d_ws, size_t ws_size,
                              hipStream_t stream) {
  const float* x   = (const float*)d_in[0];
  const float* wf  = (const float*)d_in[1];
  const float* bfo = (const float*)d_in[2];
  const float* wb  = (const float*)d_in[3];
  const float* bb  = (const float*)d_in[4];
  float* out = (float*)d_out;
  char* ws = (char*)d_ws;

  // workspace layout (bytes):
  bf16*     xT   = (bf16*)(ws);                  // 67,108,864
  unsigned* P    = (unsigned*)(ws + 67108864);   // 134,217,728 (replaces hg)
  bf16*     Wfm  = (bf16*)(ws + 201326592);      // 1,048,576
  float*    bias = (float*)(ws + 202375168);     // 4,096
  float*    Asum = (float*)(ws + 202379264);     // 4,194,304
  float*    Bsum = (float*)(ws + 206573568);     // 4,194,304
  float*    hin  = (float*)(ws + 210767872);     // 4,194,304
  float*    SA   = (float*)(ws + 214962176);     // 262,144
  float*    SB   = (float*)(ws + 215224320);     // 262,144
  float*    hsc  = (float*)(ws + 215486464);     // 262,144  (total ~215.7 MB)

  k_wconv<<<2048, 256, 0, stream>>>(wf, bfo, wb, bb, Wfm, bias);
  k_xpose<<<dim3(SEQ / 64, DIN / 64, BATCH), 256, 0, stream>>>(x, xT);
  k_gemm<<<dim3(ECH / 128, SEQ / 128, BATCH), 256, 0, stream>>>(xT, Wfm, bias, P,
                                                                Asum, Bsum);
  k_scan2a<<<dim3(NSC, 16), 256, 0, stream>>>(Asum, Bsum, SA, SB);
  k_scan2b<<<16, 256, 0, stream>>>(SA, SB, hsc);
  k_scan2c<<<dim3(NSC, 16), 256, 0, stream>>>(Asum, Bsum, hsc, hin);
  k_scan3<<<dim3(NCHNK, 2, BATCH), 256, 0, stream>>>(P, hin, out);
}

// Round 8
// 376.023 us; speedup vs baseline: 1.0297x; 1.0164x over previous
//
#include <hip/hip_runtime.h>

#define BATCH 8
#define DIN   512
#define SEQ   8192
#define ECH   1024   // concatenated conv output channels (fore 512 | back 512)
#define HCH   256    // per-direction hidden channels
#define CL    32     // scan chunk length
#define NCHNK (SEQ / CL)   // 256 chunks per row
#define NSC   16           // superchunks (16 chunks each)

typedef __bf16 bf16;
typedef __bf16 bf16x8 __attribute__((ext_vector_type(8)));
typedef float  floatx4 __attribute__((ext_vector_type(4)));

__device__ __forceinline__ void async_ld16(void* lds, const void* g) {
  __builtin_amdgcn_global_load_lds(
      (const __attribute__((address_space(1))) unsigned int*)g,
      (__attribute__((address_space(3))) unsigned int*)lds, 16, 0, 0);
}

__device__ __forceinline__ float bits2f(unsigned u) {
  return __builtin_bit_cast(float, u);
}

// minGRU step: a = sigmoid(-g), bt = sigmoid(g) * (h>=0 ? 1+h : exp(h))
__device__ __forceinline__ void gru_ab(unsigned v, float& a, float& bt) {
  float hh = bits2f(v << 16);
  float g  = bits2f(v & 0xffff0000u);
  float eg = __expf(-g);
  float sg = 1.f / (1.f + eg);   // sigmoid(g)
  a = eg * sg;                    // sigmoid(-g)
  float gv = hh >= 0.f ? 1.f + hh : __expf(hh);
  bt = sg * gv;
}

// ---------------------------------------------------------------------------
// Kernel 1: convert/permute weights to bf16 in MFMA-FRAGMENT-MAJOR order:
// element (n,d) at
//   Wf[ ((n>>4)*16 + (d>>5))*512 + (((d>>3)&3)*16 + (n&15))*8 + (d&7) ]
// so one wave's fragment load is a single contiguous 1 KB global_load_dwordx4
// -> B never needs LDS staging. (Verified rounds 4/5/7.)
// ---------------------------------------------------------------------------
__global__ void k_wconv(const float* __restrict__ wf, const float* __restrict__ bfo,
                        const float* __restrict__ wb, const float* __restrict__ bb,
                        bf16* __restrict__ Wf, float* __restrict__ bias) {
  int idx = blockIdx.x * 256 + threadIdx.x;
  if (idx < ECH * DIN) {
    int n = idx >> 9, d = idx & 511;
    int dir = n >> 9, r = n & 511, e = r >> 1, isg = r & 1;
    int s = e + (isg ? HCH : 0);
    const float* w = dir ? wb : wf;
    size_t o = ((size_t)((n >> 4) * 16 + (d >> 5)) << 9) +
               ((((d >> 3) & 3) * 16 + (n & 15)) << 3) + (d & 7);
    Wf[o] = (bf16)w[s * DIN + d];
  }
  if (idx < ECH) {
    int dir = idx >> 9, r = idx & 511, e = r >> 1, isg = r & 1;
    int s = e + (isg ? HCH : 0);
    bias[idx] = (dir ? bb : bfo)[s];
  }
}

// ---------------------------------------------------------------------------
// Kernel 2: tiled transpose + convert  x[b,d,l] fp32 -> xT[b,l,d] bf16
// (round-0 verbatim; merged-prep variant measured +6 us slower in R6)
// ---------------------------------------------------------------------------
__global__ void k_xpose(const float* __restrict__ x, bf16* __restrict__ xT) {
  __shared__ float T[64 * 65];
  int t = threadIdx.x;
  int l0 = blockIdx.x * 64;
  int d0 = blockIdx.y * 64;
  int b  = blockIdx.z;
  const float* xb = x + (size_t)b * DIN * SEQ;
#pragma unroll
  for (int p = 0; p < 4; ++p) {
    int dl = (t >> 4) + p * 16;
    int l4 = (t & 15) * 4;
    float4 v = *(const float4*)(xb + (size_t)(d0 + dl) * SEQ + l0 + l4);
    T[dl * 65 + l4 + 0] = v.x;
    T[dl * 65 + l4 + 1] = v.y;
    T[dl * 65 + l4 + 2] = v.z;
    T[dl * 65 + l4 + 3] = v.w;
  }
  __syncthreads();
  bf16* xTb = xT + (size_t)b * SEQ * DIN;
#pragma unroll
  for (int p = 0; p < 2; ++p) {
    int ll = (t >> 3) + p * 32;
    int d8 = (t & 7) * 8;
    bf16x8 h;
#pragma unroll
    for (int j = 0; j < 8; ++j) h[j] = (bf16)T[(d8 + j) * 65 + ll];
    *(bf16x8*)(xTb + (size_t)(l0 + ll) * DIN + d0 + d8) = h;
  }
}

// ---------------------------------------------------------------------------
// Kernel 3: bf16 MFMA GEMM  hg[b,l,n] = sum_d xT[b,l,d] * Wf[frag(n,d)] + bias[n]
// ROUND-5 VERIFIED VERBATIM (best measured: 100.1 us, WRITE=139264KB exactly,
// no spill at (256,3), conflicts 0). 128x128 tile, 4 waves, BK=64; A via
// XOR-swizzled global_load_lds; B from fragment-major global (L2-hot).
// R7's prefix-store epilogue measured +11 us GEMM for zero scan3 gain ->
// reverted to hg store + Cs-read composition.
// ---------------------------------------------------------------------------
#define BKK 64
#define NKT (DIN / BKK)     // 8 K-tiles

__launch_bounds__(256, 3)
__global__ void k_gemm(const bf16* __restrict__ xT, const bf16* __restrict__ Wf,
                       const float* __restrict__ bias, bf16* __restrict__ hg,
                       float* __restrict__ Asum, float* __restrict__ Bsum) {
  // staging: As[128][64] (8192 elems); epilogue: Cs[128][132] overlay
  __shared__ __align__(16) bf16 lds[16896];
  bf16* As = lds;

  int t = threadIdx.x;
  int lane = t & 63, wave = t >> 6;
  int l15 = lane & 15, quad = lane >> 4, rsw = l15 & 7;
  int wm = wave >> 1, wn = wave & 1;
  int mb = wm * 64, nb = wn * 64;

  // XCD-locality remap (round-0): all 8 n-tiles of one l-tile on one XCD.
  int lin = blockIdx.x + 8 * blockIdx.y;   // 0..511
  int xcd = lin & 7;
  int seq = lin >> 3;                      // 0..63
  int ltile = xcd + 8 * (seq >> 3);        // 0..63
  int ntile = seq & 7;
  int n0 = ntile * 128;
  int l0 = ltile * 128;
  int b  = blockIdx.z;

  const bf16* gA = xT + ((size_t)b * SEQ + l0) * DIN;
  int nb16 = (n0 >> 4) + wn * 4;           // this wave's base 16-row B block

  float bb4[4];
#pragma unroll
  for (int ni = 0; ni < 4; ++ni) bb4[ni] = bias[n0 + nb + ni * 16 + l15];

  int srow = wave * 32 + (lane >> 3);
  int scol = ((lane & 7) ^ ((lane >> 3) & 7)) * 8;   // XOR-preswizzled src col

  floatx4 acc[4][4];
#pragma unroll
  for (int i = 0; i < 4; ++i)
#pragma unroll
    for (int j = 0; j < 4; ++j) acc[i][j] = (floatx4){0.f, 0.f, 0.f, 0.f};

#pragma unroll
  for (int kt = 0; kt < NKT; ++kt) {
    int k0 = kt * BKK;
    // stage A(kt): 4 global_load_lds per thread, linear LDS dest
    // (wave-uniform base + lane*16B), XOR-preswizzled global source col.
#pragma unroll
    for (int q = 0; q < 4; ++q)
      async_ld16(As + (wave * 32 + q * 8) * 64,
                 gA + (size_t)(srow + q * 8) * DIN + k0 + scol);

    // B fragments for this K-tile: 8 coalesced 1KB wave-loads from L2.
    // Issued before the drain so their latency overlaps it.
    bf16x8 bfr[4][2];
#pragma unroll
    for (int i = 0; i < 4; ++i)
#pragma unroll
      for (int k2 = 0; k2 < 2; ++k2)
        bfr[i][k2] = *(const bf16x8*)(Wf +
            (((size_t)(nb16 + i) * 16 + kt * 2 + k2) << 9) + lane * 8);

    __syncthreads();   // full drain: all waves' A(kt) visible in LDS

#pragma unroll
    for (int k2 = 0; k2 < 2; ++k2) {
      bf16x8 af[4];
#pragma unroll
      for (int i = 0; i < 4; ++i)
        af[i] = *(const bf16x8*)(As + (mb + i * 16 + l15) * 64 +
                                 (((k2 * 4 + quad) ^ rsw) * 8));
#pragma unroll
      for (int mi = 0; mi < 4; ++mi)
#pragma unroll
        for (int ni = 0; ni < 4; ++ni)
          acc[mi][ni] = __builtin_amdgcn_mfma_f32_16x16x32_bf16(
              af[mi], bfr[ni][k2], acc[mi][ni], 0, 0, 0);
    }
    __syncthreads();   // all reads done before next tile's overwrite
  }

  // epilogue: bias add, pack to bf16 in LDS (stride 132 breaks conflicts), store
  bf16* Cs = lds;  // [128][132]
#pragma unroll
  for (int mi = 0; mi < 4; ++mi)
#pragma unroll
    for (int ni = 0; ni < 4; ++ni)
#pragma unroll
      for (int r = 0; r < 4; ++r) {
        int row = mb + mi * 16 + quad * 4 + r;
        int col = nb + ni * 16 + l15;
        Cs[row * 132 + col] = (bf16)(acc[mi][ni][r] + bb4[ni]);
      }
  __syncthreads();
  bf16* hgb = hg + ((size_t)b * SEQ + l0) * ECH + n0;
#pragma unroll
  for (int p = 0; p < 8; ++p) {
    int row = p * 16 + (t >> 4);
    int seg = t & 15;
    *(bf16x8*)(hgb + (size_t)row * ECH + seg * 8) =
        *(const bf16x8*)(Cs + row * 132 + seg * 8);
  }

  // fused per-chunk minGRU composition
  // wave = chunk within tile (4 chunks of 32), lane = e-pair within tile (64)
  {
    int dirn = ntile >> 2;               // n0 >> 9
    int c = wave, el = lane;
    float A = 1.f, Bc = 0.f;
#pragma unroll 8
    for (int i = 0; i < CL; ++i) {
      int row = c * CL + (dirn ? (CL - 1 - i) : i);
      unsigned v = *(const unsigned*)(Cs + row * 132 + 2 * el);
      float a, bt;
      gru_ab(v, a, bt);
      A *= a;
      Bc = a * Bc + bt;
    }
    int chunkg = ltile * 4 + c;
    int eg = ((n0 & 511) >> 1) + el;
    size_t o = ((size_t)(b * 2 + dirn) * NCHNK + chunkg) * 256 + eg;
    Asum[o] = A;
    Bsum[o] = Bc;
  }
}

// ---------------------------------------------------------------------------
// Kernel 4a: per-superchunk (16 chunks) composition. 256 blocks x 256 thr.
// ---------------------------------------------------------------------------
__global__ void k_scan2a(const float* __restrict__ Asum, const float* __restrict__ Bsum,
                         float* __restrict__ SA, float* __restrict__ SB) {
  int e = threadIdx.x, sc = blockIdx.x, row2 = blockIdx.y, dir = row2 & 1;
  size_t base = (size_t)row2 * NCHNK;
  float Acc = 1.f, Bcc = 0.f;
#pragma unroll
  for (int i = 0; i < 16; ++i) {
    int c = sc * 16 + (dir ? 15 - i : i);
    size_t o = (base + c) * 256 + e;
    float a = Asum[o], bv = Bsum[o];
    Acc = a * Acc;
    Bcc = a * Bcc + bv;
  }
  size_t so = ((size_t)row2 * NSC + sc) * 256 + e;
  SA[so] = Acc;
  SB[so] = Bcc;
}

// ---------------------------------------------------------------------------
// Kernel 4b: scan the 16 superchunks per row. 16 blocks x 256 thr.
// ---------------------------------------------------------------------------
__global__ void k_scan2b(const float* __restrict__ SA, const float* __restrict__ SB,
                         float* __restrict__ hsc) {
  int e = threadIdx.x, row2 = blockIdx.x, dir = row2 & 1;
  float h = 0.f;
  for (int i = 0; i < NSC; ++i) {
    int sc = dir ? NSC - 1 - i : i;
    size_t o = ((size_t)row2 * NSC + sc) * 256 + e;
    hsc[o] = h;
    h = SA[o] * h + SB[o];
  }
}

// ---------------------------------------------------------------------------
// Kernel 4c: distribute carries to every chunk. 256 blocks x 256 thr.
// ---------------------------------------------------------------------------
__global__ void k_scan2c(const float* __restrict__ Asum, const float* __restrict__ Bsum,
                         const float* __restrict__ hsc, float* __restrict__ hin) {
  int e = threadIdx.x, sc = blockIdx.x, row2 = blockIdx.y, dir = row2 & 1;
  float h = hsc[((size_t)row2 * NSC + sc) * 256 + e];
#pragma unroll
  for (int i = 0; i < 16; ++i) {
    int c = sc * 16 + (dir ? 15 - i : i);
    size_t o = ((size_t)row2 * NCHNK + c) * 256 + e;
    hin[o] = h;
    h = Asum[o] * h + Bsum[o];
  }
}

// ---------------------------------------------------------------------------
// Kernel 5: recompute local scan with carry-in, transpose via LDS (stride 33),
// write out[b, dir*256+e, l] as coalesced float4.
// CHANGE vs R0 (G13 load-width): chain phase now 128 threads x 2 chains each
// with 8B dwordx2 hg loads (512B/wave-instr) instead of 256 threads x 1 chain
// at 4B/lane. Same T layout, same write phase, identical math; 2 independent
// chains/lane also double exp-latency-hiding ILP.
// ---------------------------------------------------------------------------
__global__ void k_scan3(const bf16* __restrict__ hg, const float* __restrict__ hin,
                        float* __restrict__ out) {
  __shared__ float T[256 * 33];
  int t = threadIdx.x;
  int chunk = blockIdx.x, dir = blockIdx.y, b = blockIdx.z;
  int row2 = b * 2 + dir;
  int lbase = chunk * CL;
  if (t < 128) {
    int J = t;                               // handles e-pairs 2J, 2J+1
    const bf16* hb = hg + (size_t)(b * SEQ + lbase) * ECH + dir * 512 + 4 * J;
    const float* hb0 = hin + ((size_t)row2 * NCHNK + chunk) * 256 + 2 * J;
    float h0 = hb0[0];
    float h1 = hb0[1];
#pragma unroll 8
    for (int i = 0; i < CL; ++i) {
      int ll = dir ? (CL - 1 - i) : i;
      uint2 v2 = *(const uint2*)(hb + (size_t)ll * ECH);   // pairs 2J,2J+1: 8B
      float a0, b0v, a1, b1v;
      gru_ab(v2.x, a0, b0v);
      gru_ab(v2.y, a1, b1v);
      h0 = a0 * h0 + b0v;
      h1 = a1 * h1 + b1v;
      T[(2 * J + 0) * 33 + ll] = h0;
      T[(2 * J + 1) * 33 + ll] = h1;
    }
  }
  __syncthreads();
  float* ob = out + ((size_t)b * 512 + dir * 256) * SEQ + lbase;
#pragma unroll
  for (int p = 0; p < 8; ++p) {
    int row = p * 32 + (t >> 3);   // e channel
    int c4 = (t & 7) * 4;          // l within chunk
    float4 v4;
    v4.x = T[row * 33 + c4 + 0];
    v4.y = T[row * 33 + c4 + 1];
    v4.z = T[row * 33 + c4 + 2];
    v4.w = T[row * 33 + c4 + 3];
    *(float4*)(ob + (size_t)row * SEQ + c4) = v4;
  }
}

// ---------------------------------------------------------------------------
extern "C" void kernel_launch(void* const* d_in, const int* in_sizes, int n_in,
                              void* d_out, int out_size, void* d_ws, size_t ws_size,
                              hipStream_t stream) {
  const float* x   = (const float*)d_in[0];
  const float* wf  = (const float*)d_in[1];
  const float* bfo = (const float*)d_in[2];
  const float* wb  = (const float*)d_in[3];
  const float* bb  = (const float*)d_in[4];
  float* out = (float*)d_out;
  char* ws = (char*)d_ws;

  // workspace layout (bytes):
  bf16*  xT   = (bf16*)(ws);                       // 67,108,864
  bf16*  hg   = (bf16*)(ws + 67108864);            // 134,217,728
  bf16*  Wfm  = (bf16*)(ws + 201326592);           // 1,048,576
  float* bias = (float*)(ws + 202375168);          // 4,096
  float* Asum = (float*)(ws + 202379264);          // 4,194,304
  float* Bsum = (float*)(ws + 206573568);          // 4,194,304
  float* hin  = (float*)(ws + 210767872);          // 4,194,304
  float* SA   = (float*)(ws + 214962176);          // 262,144
  float* SB   = (float*)(ws + 215224320);          // 262,144
  float* hsc  = (float*)(ws + 215486464);          // 262,144  (total ~215.7 MB)

  k_wconv<<<2048, 256, 0, stream>>>(wf, bfo, wb, bb, Wfm, bias);
  k_xpose<<<dim3(SEQ / 64, DIN / 64, BATCH), 256, 0, stream>>>(x, xT);
  k_gemm<<<dim3(ECH / 128, SEQ / 128, BATCH), 256, 0, stream>>>(xT, Wfm, bias, hg,
                                                                Asum, Bsum);
  k_scan2a<<<dim3(NSC, 16), 256, 0, stream>>>(Asum, Bsum, SA, SB);
  k_scan2b<<<16, 256, 0, stream>>>(SA, SB, hsc);
  k_scan2c<<<dim3(NSC, 16), 256, 0, stream>>>(Asum, Bsum, hsc, hin);
  k_scan3<<<dim3(NCHNK, 2, BATCH), 256, 0, stream>>>(hg, hin, out);
}